// Round 15
// baseline (293.844 us; speedup 1.0000x reference)
//
#include <hip/hip_runtime.h>

#define Dh 128
#define NN 50000
#define EE 800000
#define RR 8
#define BB 4
#define LL 2
#define KTOT 640          // 4*128 (basis-agg) + 128 (self h)
#define KA0 512           // cols in aggB
#define BN_EPS 1e-3f
#define NR (NN * RR)
#define NBLK 196          // (NN+255)/256
#define NGRP 12500        // node groups of 4 (one wave each)
#define AGG_BLOCKS 2048   // grid-stride: 8 resident blocks/CU

// prep_kernel range sizes
#define N8    (NN * Dh / 8)        // 800000  nf convert (8 elems/thread)
#define BT_N  (LL * Dh * KTOT)     // 163840  BT build
#define WE_N  (Dh * Dh)            // 16384   WembT build
#define EPI_N (3 * Dh)             // 384     epilogue scale/shift
#define Z4_N  (NR / 4)             // 100000  counts zeroing (int4/thread)
#define PREP_TOT (N8 + BT_N + WE_N + EPI_N + Z4_N)   // 1080608

typedef __attribute__((ext_vector_type(8))) short bf16x8;
typedef __attribute__((ext_vector_type(4))) float f32x4;
typedef __attribute__((ext_vector_type(2))) float f32x2;

__device__ inline unsigned short f2bf(float x) {
    unsigned u = __float_as_uint(x);
    unsigned r = (u + 0x7fffu + ((u >> 16) & 1u)) >> 16;
    return (unsigned short)r;
}

// ---------------------------------------------------------------------------
// Fused prep: nf->bf16, BT build, WembT build, epilogue consts, counts zero.
// ---------------------------------------------------------------------------
__global__ __launch_bounds__(256) void prep_kernel(
    const float* __restrict__ nf, const float* __restrict__ bases,
    const float* __restrict__ self_loop, const float* __restrict__ W_emb,
    const float* __restrict__ b_emb,
    const float* __restrict__ bn_gamma, const float* __restrict__ bn_beta,
    const float* __restrict__ bn_mean, const float* __restrict__ bn_var,
    unsigned short* __restrict__ nf_bf, unsigned short* __restrict__ BT,
    unsigned short* __restrict__ WembT,
    float* __restrict__ sc, float* __restrict__ sh, int* __restrict__ counts)
{
    int idx = blockIdx.x * 256 + threadIdx.x;
    if (idx < N8) {
        size_t base = (size_t)idx * 8;
        float4 v0 = *(const float4*)&nf[base];
        float4 v1 = *(const float4*)&nf[base + 4];
        unsigned short o[8] = { f2bf(v0.x), f2bf(v0.y), f2bf(v0.z), f2bf(v0.w),
                                f2bf(v1.x), f2bf(v1.y), f2bf(v1.z), f2bf(v1.w) };
        *(uint4*)&nf_bf[base] = *(uint4*)o;
        return;
    }
    idx -= N8;
    if (idx < BT_N) {
        int l = idx / (Dh * KTOT);
        int rem = idx - l * (Dh * KTOT);
        int f = rem / KTOT;
        int k = rem - f * KTOT;
        float v;
        if (k < KA0) v = bases[(((l * BB + (k >> 7)) * Dh) + (k & 127)) * Dh + f];
        else         v = self_loop[((size_t)l * Dh + (k - KA0)) * Dh + f];
        BT[(size_t)(l * Dh + f) * KTOT + k] = f2bf(v);
        return;
    }
    idx -= BT_N;
    if (idx < WE_N) {
        int f = idx >> 7, d = idx & 127;
        WembT[f * Dh + d] = f2bf(W_emb[d * Dh + f]);
        return;
    }
    idx -= WE_N;
    if (idx < EPI_N) {
        int cfg = idx >> 7, d = idx & 127;
        float s, t;
        if (cfg == 0) { s = 1.f; t = b_emb[d]; }
        else {
            int l = cfg - 1;
            float sv = bn_gamma[l * Dh + d] * rsqrtf(bn_var[l * Dh + d] + BN_EPS);
            s = sv;
            t = bn_beta[l * Dh + d] - bn_mean[l * Dh + d] * sv;
        }
        sc[cfg * Dh + d] = s; sh[cfg * Dh + d] = t;
        return;
    }
    idx -= EPI_N;
    if (idx < Z4_N) ((int4*)counts)[idx] = make_int4(0, 0, 0, 0);
}

// ---------------------------------------------------------------------------
// 64x128-tile GEMM, K multiple of 64, PLAIN staging (stage->sync->MFMA->sync).
// A = [A0 (ka0 cols) | A1 (128 cols)], BT[f][k]. Epilogue y=x*sc+sh, opt ReLU.
// ---------------------------------------------------------------------------
__global__ __launch_bounds__(256) void gemm_bn_kernel(
    const unsigned short* __restrict__ A0, int ka0,
    const unsigned short* __restrict__ A1,
    const unsigned short* __restrict__ BT, int K,
    const float* __restrict__ sc, const float* __restrict__ sh,
    void* __restrict__ outp, int out_fp32, int do_relu, int M)
{
    __shared__ unsigned short a_s[64][72];    //  9 KB (144B stride -> 2-way, free)
    __shared__ unsigned short b_s[128][72];   // 18 KB
    int t = threadIdx.x;
    int wave = t >> 6, lane = t & 63;
    int n16 = lane & 15, quad = lane >> 4;
    int row0 = blockIdx.x * 64;

    f32x4 acc[8];
    #pragma unroll
    for (int j = 0; j < 8; j++) acc[j] = (f32x4){0.f, 0.f, 0.f, 0.f};

    int nchunk = K >> 6;
    for (int ch = 0; ch < nchunk; ch++) {
        int k0 = ch * 64;
        // stage A: thread -> row t>>2, 16-col segment t&3 (2 uint4)
        {
            int srow = t >> 2, seg = t & 3;
            int gr = row0 + srow;
            int kk = k0 + seg * 16;
            const uint4* gp;
            if (kk < ka0) gp = (const uint4*)&A0[(size_t)gr * ka0 + kk];
            else          gp = (const uint4*)&A1[(size_t)gr * Dh + (kk - ka0)];
            #pragma unroll
            for (int i = 0; i < 2; i++) {
                uint4 v = make_uint4(0u, 0u, 0u, 0u);
                if (gr < M) v = gp[i];
                *(uint4*)&a_s[srow][seg * 16 + i * 8] = v;
            }
        }
        // stage B: thread -> row t>>1, 32-col segment t&1 (4 uint4)
        {
            int f = t >> 1, seg = t & 1;
            const uint4* bp = (const uint4*)&BT[(size_t)f * K + k0 + seg * 32];
            #pragma unroll
            for (int i = 0; i < 4; i++)
                *(uint4*)&b_s[f][seg * 32 + i * 8] = bp[i];
        }
        __syncthreads();
        #pragma unroll
        for (int ks = 0; ks < 2; ks++) {
            bf16x8 af, bfr[8];
            af = *(const bf16x8*)&a_s[wave * 16 + n16][ks * 32 + quad * 8];
            #pragma unroll
            for (int j = 0; j < 8; j++)
                bfr[j] = *(const bf16x8*)&b_s[j * 16 + n16][ks * 32 + quad * 8];
            #pragma unroll
            for (int j = 0; j < 8; j++)
                acc[j] = __builtin_amdgcn_mfma_f32_16x16x32_bf16(
                    af, bfr[j], acc[j], 0, 0, 0);
        }
        __syncthreads();
    }

    float sj[8], tj[8];
    #pragma unroll
    for (int j = 0; j < 8; j++) {
        int col = j * 16 + n16;
        sj[j] = sc[col]; tj[j] = sh[col];
    }
    #pragma unroll
    for (int v = 0; v < 4; v++) {
        int gr = row0 + wave * 16 + quad * 4 + v;
        if (gr < M) {
            #pragma unroll
            for (int j = 0; j < 8; j++) {
                float y = acc[j][v] * sj[j] + tj[j];
                if (do_relu) y = fmaxf(y, 0.f);
                int col = j * 16 + n16;
                if (out_fp32) ((float*)outp)[(size_t)gr * Dh + col] = y;
                else ((unsigned short*)outp)[(size_t)gr * Dh + col] = f2bf(y);
            }
        }
    }
}

// ---------------------------------------------------------------------------
// count: per-(dst,etype) histogram; atomic return value = edge rank within
// its bucket (enables atomic-free fill; round-9 measured win).
// ---------------------------------------------------------------------------
__global__ __launch_bounds__(256) void count_kernel(
    const int* __restrict__ dst, const int* __restrict__ etype,
    int* __restrict__ counts, unsigned short* __restrict__ rank)
{
    int idx = blockIdx.x * 256 + threadIdx.x;   // [0, EE/4)
    if (idx >= EE / 4) return;
    int4 d = ((const int4*)dst)[idx];
    int4 t = ((const int4*)etype)[idx];
    int r0 = atomicAdd(&counts[d.x * RR + t.x], 1);
    int r1 = atomicAdd(&counts[d.y * RR + t.y], 1);
    int r2 = atomicAdd(&counts[d.z * RR + t.z], 1);
    int r3 = atomicAdd(&counts[d.w * RR + t.w], 1);
    ((ushort4*)rank)[idx] = make_ushort4((unsigned short)r0, (unsigned short)r1,
                                         (unsigned short)r2, (unsigned short)r3);
}

// fused: per-node norm + degree + block-level exclusive scan.
// Also converts counts[n*8+r] IN PLACE to the exclusive per-type prefix.
__global__ __launch_bounds__(256) void norm_scan1_kernel(
    int* __restrict__ counts, float* __restrict__ node_norm,
    int* __restrict__ row_ptr, int* __restrict__ bsum)
{
    __shared__ int s[256];
    int t = threadIdx.x;
    int n = blockIdx.x * 256 + t;
    int total = 0; float norm = 0.f;
    if (n < NN) {
        int pre[RR];
        #pragma unroll
        for (int r = 0; r < RR; r++) {
            int c = counts[n * RR + r];
            pre[r] = total;                      // exclusive prefix
            total += c;
            if (c > 0) norm = 1.0f / (float)c;   // later r overwrites (ref semantics)
        }
        #pragma unroll
        for (int r = 0; r < RR; r++) counts[n * RR + r] = pre[r];
        node_norm[n] = norm;
    }
    s[t] = total;
    __syncthreads();
    #pragma unroll
    for (int off = 1; off < 256; off <<= 1) {
        int v = (t >= off) ? s[t - off] : 0;
        __syncthreads();
        s[t] += v;
        __syncthreads();
    }
    if (n < NN) row_ptr[n] = s[t] - total;
    if (t == 255) bsum[blockIdx.x] = s[255];
}

// scan2 folded in: every block redundantly prefix-scans the 196 bsums in LDS
// (196 ints -- trivial), removing the former 1-block scan2 dispatch bubble.
// Finalizes row_ptr AND folds the global row base into the per-type offsets.
__global__ __launch_bounds__(256) void scan3_kernel(
    int* __restrict__ row_ptr, int* __restrict__ counts,
    const int* __restrict__ bsum)
{
    __shared__ int s[256];
    int t = threadIdx.x;
    int d = (t < NBLK) ? bsum[t] : 0;
    s[t] = d;
    __syncthreads();
    #pragma unroll
    for (int off = 1; off < 256; off <<= 1) {
        int v = (t >= off) ? s[t - off] : 0;
        __syncthreads();
        s[t] += v;
        __syncthreads();
    }
    int bid = blockIdx.x;
    int boff = (bid == 0) ? 0 : s[bid - 1];      // exclusive block offset
    int n = bid * 256 + t;
    if (n < NN) {
        int v = row_ptr[n] + boff;
        row_ptr[n] = v;
        #pragma unroll
        for (int r = 0; r < RR; r++) counts[n * RR + r] += v;
    }
    if (bid == 0 && t == 0) row_ptr[NN] = EE;
}

// atomic-free fill: pos = counts[dst*8+et] + rank[e].
__global__ __launch_bounds__(256) void fill_kernel(
    const int* __restrict__ src, const int* __restrict__ dst,
    const int* __restrict__ etype, const unsigned short* __restrict__ rank,
    const int* __restrict__ counts, unsigned* __restrict__ packed)
{
    int idx = blockIdx.x * 256 + threadIdx.x;   // [0, EE/4)
    if (idx >= EE / 4) return;
    int4 d  = ((const int4*)dst)[idx];
    int4 sr = ((const int4*)src)[idx];
    int4 et = ((const int4*)etype)[idx];
    ushort4 rk = ((const ushort4*)rank)[idx];
    int p0 = counts[d.x * RR + et.x] + rk.x;
    int p1 = counts[d.y * RR + et.y] + rk.y;
    int p2 = counts[d.z * RR + et.z] + rk.z;
    int p3 = counts[d.w * RR + et.w] + rk.w;
    packed[p0] = (unsigned)sr.x | ((unsigned)et.x << 16);
    packed[p1] = (unsigned)sr.y | ((unsigned)et.y << 16);
    packed[p2] = (unsigned)sr.z | ((unsigned)et.z << 16);
    packed[p3] = (unsigned)sr.w | ((unsigned)et.w << 16);
}

// ---------------------------------------------------------------------------
// Basis-space aggregation: one wave per node, lane owns cols (2l, 2l+1).
//   aggB[n, b, :] = norm[n] * sum_{e into n} w_coe[et_e, b] * h[src_e, :]
// Inner loop = round-13 measured best (8-wide, f32x2 pk_fma, masked tail).
// GRID-STRIDE: 2048 resident blocks loop over 12500 node-groups. r14 counters
// showed occupancy 55-62% with NO resource limit -> 12500 x 0.57us blocks
// lose ~1/3 to dispatch churn; resident waves eliminate it.
// ---------------------------------------------------------------------------
__global__ __launch_bounds__(256) void agg_basis_kernel(
    const unsigned* __restrict__ h32, const int* __restrict__ row_ptr,
    const unsigned* __restrict__ packed, const float* __restrict__ node_norm,
    const float* __restrict__ wco,         // this layer's [8][4] coefficients
    unsigned* __restrict__ aggB)           // [NN][256] u32 = [NN][512] bf16
{
    __shared__ float4 co_s[RR];
    int t = threadIdx.x;
    if (t < RR) co_s[t] = ((const float4*)wco)[t];
    __syncthreads();
    int wave = t >> 6, lane = t & 63;
    for (int g = blockIdx.x; g < NGRP; g += AGG_BLOCKS) {
        int n = g * 4 + wave;
        if (n >= NN) continue;
        int s = row_ptr[n];
        int e = row_ptr[n + 1];
        f32x2 a[BB];
        #pragma unroll
        for (int b = 0; b < BB; b++) a[b] = (f32x2){0.f, 0.f};
        int i = s;
        for (; i + 8 <= e; i += 8) {
            unsigned p[8], hv[8];
            #pragma unroll
            for (int k = 0; k < 8; k++) p[k] = packed[i + k];
            #pragma unroll
            for (int k = 0; k < 8; k++)
                hv[k] = h32[(size_t)(p[k] & 0xffffu) * 64 + lane];
            #pragma unroll
            for (int k = 0; k < 8; k++) {
                float4 co = co_s[p[k] >> 16];
                f32x2 v = (f32x2){ __uint_as_float(hv[k] << 16),
                                   __uint_as_float(hv[k] & 0xffff0000u) };
                a[0] += co.x * v;
                a[1] += co.y * v;
                a[2] += co.z * v;
                a[3] += co.w * v;
            }
        }
        if (i < e) {
            unsigned p[8], hv[8];
            #pragma unroll
            for (int k = 0; k < 8; k++) {
                int j = i + k;
                p[k] = packed[j < e ? j : (e - 1)];
            }
            #pragma unroll
            for (int k = 0; k < 8; k++)
                hv[k] = h32[(size_t)(p[k] & 0xffffu) * 64 + lane];
            #pragma unroll
            for (int k = 0; k < 8; k++) {
                float vm = (i + k < e) ? 1.f : 0.f;
                float4 co = co_s[p[k] >> 16];
                f32x2 v = (f32x2){ __uint_as_float(hv[k] << 16) * vm,
                                   __uint_as_float(hv[k] & 0xffff0000u) * vm };
                a[0] += co.x * v;
                a[1] += co.y * v;
                a[2] += co.z * v;
                a[3] += co.w * v;
            }
        }
        float norm = node_norm[n];
        #pragma unroll
        for (int b = 0; b < BB; b++) {
            unsigned o = (unsigned)f2bf(a[b].x * norm) |
                         ((unsigned)f2bf(a[b].y * norm) << 16);
            aggB[(size_t)n * 256 + b * 64 + lane] = o;
        }
    }
}

// ---------------------------------------------------------------------------
extern "C" void kernel_launch(void* const* d_in, const int* in_sizes, int n_in,
                              void* d_out, int out_size, void* d_ws, size_t ws_size,
                              hipStream_t stream)
{
    const float* node_feat = (const float*)d_in[0];
    const float* W_emb     = (const float*)d_in[1];
    const float* b_emb     = (const float*)d_in[2];
    const float* bases     = (const float*)d_in[3];
    const float* w_coe     = (const float*)d_in[4];
    const float* self_loop = (const float*)d_in[5];
    const float* bn_gamma  = (const float*)d_in[6];
    const float* bn_beta   = (const float*)d_in[7];
    const float* bn_mean   = (const float*)d_in[8];
    const float* bn_var    = (const float*)d_in[9];
    const int*   src       = (const int*)d_in[10];
    const int*   dst       = (const int*)d_in[11];
    const int*   etype     = (const int*)d_in[12];

    char* ws = (char*)d_ws;
    size_t off = 0;
    unsigned short* h0 = (unsigned short*)(ws + off);     off += (size_t)NN * Dh * 2;        // 12.8 MB
    unsigned short* h1 = (unsigned short*)(ws + off);     off += (size_t)NN * Dh * 2;        // 12.8 MB
    unsigned short* nf_bf = (unsigned short*)(ws + off);  off += (size_t)NN * Dh * 2;        // 12.8 MB
    unsigned short* aggB = (unsigned short*)(ws + off);   off += (size_t)NN * KA0 * 2;       // 51.2 MB
    unsigned short* BT = (unsigned short*)(ws + off);     off += (size_t)LL * Dh * KTOT * 2; // 320 KB
    unsigned short* WembT = (unsigned short*)(ws + off);  off += (size_t)Dh * Dh * 2;        // 32 KB
    float* sc = (float*)(ws + off);                       off += 3 * Dh * 4;
    float* sh = (float*)(ws + off);                       off += 3 * Dh * 4;
    float* node_norm = (float*)(ws + off);                off += (size_t)NN * 4;
    int* counts = (int*)(ws + off);                       off += (size_t)NR * 4;             // 1.6 MB
    int* row_ptr = (int*)(ws + off);                      off += ((size_t)NN + 4) * 4;
    unsigned short* rank = (unsigned short*)(ws + off);   off += (size_t)EE * 2;             // 1.6 MB
    int* bsum = (int*)(ws + off);                         off += 256 * 4;
    unsigned* packed = (unsigned*)(ws + off);             off += (size_t)EE * 4 + 64;        // 3.2 MB

    const int e4_blocks = (EE / 4 + 255) / 256;      // 782
    const int node_blocks = (NN + 255) / 256;        // 196
    const int prep_blocks = (PREP_TOT + 255) / 256;  // 4222
    const int gemm_blocks = (NN + 63) / 64;          // 782

    // fused prep (nf cast, BT, WembT, epilogue, counts zero)
    prep_kernel<<<prep_blocks, 256, 0, stream>>>(
        node_feat, bases, self_loop, W_emb, b_emb,
        bn_gamma, bn_beta, bn_mean, bn_var,
        nf_bf, BT, WembT, sc, sh, counts);

    // graph structure
    count_kernel<<<e4_blocks, 256, 0, stream>>>(dst, etype, counts, rank);
    norm_scan1_kernel<<<node_blocks, 256, 0, stream>>>(counts, node_norm, row_ptr, bsum);
    scan3_kernel<<<node_blocks, 256, 0, stream>>>(row_ptr, counts, bsum);
    fill_kernel<<<e4_blocks, 256, 0, stream>>>(src, dst, etype, rank, counts, packed);

    // embed: h0 = bf16(nf @ W_emb + b_emb)
    gemm_bn_kernel<<<gemm_blocks, 256, 0, stream>>>(
        nf_bf, Dh, nullptr, WembT, Dh, sc, sh, h0, 0, 0, NN);

    // layer 0
    agg_basis_kernel<<<AGG_BLOCKS, 256, 0, stream>>>(
        (const unsigned*)h0, row_ptr, packed, node_norm, w_coe, (unsigned*)aggB);
    gemm_bn_kernel<<<gemm_blocks, 256, 0, stream>>>(
        aggB, KA0, h0, BT, KTOT, sc + Dh, sh + Dh, h1, 0, 1, NN);

    // layer 1
    agg_basis_kernel<<<AGG_BLOCKS, 256, 0, stream>>>(
        (const unsigned*)h1, row_ptr, packed, node_norm, w_coe + RR * BB, (unsigned*)aggB);
    gemm_bn_kernel<<<gemm_blocks, 256, 0, stream>>>(
        aggB, KA0, h1, BT + Dh * KTOT, KTOT, sc + 2 * Dh, sh + 2 * Dh, d_out, 1, 1, NN);
}

// Round 16
// 290.983 us; speedup vs baseline: 1.0098x; 1.0098x over previous
//
#include <hip/hip_runtime.h>

#define Dh 128
#define NN 50000
#define EE 800000
#define RR 8
#define BB 4
#define LL 2
#define KTOT 640          // 4*128 (basis-agg) + 128 (self h)
#define KA0 512           // cols in aggB
#define BN_EPS 1e-3f
#define NR (NN * RR)
#define NBLK 196          // (NN+255)/256

// prep_kernel range sizes
#define N8    (NN * Dh / 8)        // 800000  nf convert (8 elems/thread)
#define BT_N  (LL * Dh * KTOT)     // 163840  BT build
#define WE_N  (Dh * Dh)            // 16384   WembT build
#define EPI_N (3 * Dh)             // 384     epilogue scale/shift
#define Z4_N  (NR / 4)             // 100000  counts zeroing (int4/thread)
#define PREP_TOT (N8 + BT_N + WE_N + EPI_N + Z4_N)   // 1080608

typedef __attribute__((ext_vector_type(8))) short bf16x8;
typedef __attribute__((ext_vector_type(4))) float f32x4;
typedef __attribute__((ext_vector_type(2))) float f32x2;

__device__ inline unsigned short f2bf(float x) {
    unsigned u = __float_as_uint(x);
    unsigned r = (u + 0x7fffu + ((u >> 16) & 1u)) >> 16;
    return (unsigned short)r;
}

// ---------------------------------------------------------------------------
// Fused prep: nf->bf16, BT build, WembT build, epilogue consts, counts zero.
// ---------------------------------------------------------------------------
__global__ __launch_bounds__(256) void prep_kernel(
    const float* __restrict__ nf, const float* __restrict__ bases,
    const float* __restrict__ self_loop, const float* __restrict__ W_emb,
    const float* __restrict__ b_emb,
    const float* __restrict__ bn_gamma, const float* __restrict__ bn_beta,
    const float* __restrict__ bn_mean, const float* __restrict__ bn_var,
    unsigned short* __restrict__ nf_bf, unsigned short* __restrict__ BT,
    unsigned short* __restrict__ WembT,
    float* __restrict__ sc, float* __restrict__ sh, int* __restrict__ counts)
{
    int idx = blockIdx.x * 256 + threadIdx.x;
    if (idx < N8) {
        size_t base = (size_t)idx * 8;
        float4 v0 = *(const float4*)&nf[base];
        float4 v1 = *(const float4*)&nf[base + 4];
        unsigned short o[8] = { f2bf(v0.x), f2bf(v0.y), f2bf(v0.z), f2bf(v0.w),
                                f2bf(v1.x), f2bf(v1.y), f2bf(v1.z), f2bf(v1.w) };
        *(uint4*)&nf_bf[base] = *(uint4*)o;
        return;
    }
    idx -= N8;
    if (idx < BT_N) {
        int l = idx / (Dh * KTOT);
        int rem = idx - l * (Dh * KTOT);
        int f = rem / KTOT;
        int k = rem - f * KTOT;
        float v;
        if (k < KA0) v = bases[(((l * BB + (k >> 7)) * Dh) + (k & 127)) * Dh + f];
        else         v = self_loop[((size_t)l * Dh + (k - KA0)) * Dh + f];
        BT[(size_t)(l * Dh + f) * KTOT + k] = f2bf(v);
        return;
    }
    idx -= BT_N;
    if (idx < WE_N) {
        int f = idx >> 7, d = idx & 127;
        WembT[f * Dh + d] = f2bf(W_emb[d * Dh + f]);
        return;
    }
    idx -= WE_N;
    if (idx < EPI_N) {
        int cfg = idx >> 7, d = idx & 127;
        float s, t;
        if (cfg == 0) { s = 1.f; t = b_emb[d]; }
        else {
            int l = cfg - 1;
            float sv = bn_gamma[l * Dh + d] * rsqrtf(bn_var[l * Dh + d] + BN_EPS);
            s = sv;
            t = bn_beta[l * Dh + d] - bn_mean[l * Dh + d] * sv;
        }
        sc[cfg * Dh + d] = s; sh[cfg * Dh + d] = t;
        return;
    }
    idx -= EPI_N;
    if (idx < Z4_N) ((int4*)counts)[idx] = make_int4(0, 0, 0, 0);
}

// ---------------------------------------------------------------------------
// 64x128-tile GEMM, K multiple of 64, register-prefetch double buffer done
// SCRATCH-PROOF (r5 lesson: lambda/array prefetch spilled; here: straight-line
// NAMED uint4 regs, statically addressed). Loads for chunk ch+1 issue right
// after the barrier, hiding global latency under the 16-MFMA block of chunk ch.
// A = [A0 (ka0 cols) | A1 (128 cols)], BT[f][k]. Epilogue y=x*sc+sh, opt ReLU.
// Tripwire: WRITE_SIZE >> 26MB means spill -> revert.
// ---------------------------------------------------------------------------
__global__ __launch_bounds__(256) void gemm_bn_kernel(
    const unsigned short* __restrict__ A0, int ka0,
    const unsigned short* __restrict__ A1,
    const unsigned short* __restrict__ BT, int K,
    const float* __restrict__ sc, const float* __restrict__ sh,
    void* __restrict__ outp, int out_fp32, int do_relu, int M)
{
    __shared__ unsigned short a_s[64][72];    //  9 KB (144B stride -> 2-way, free)
    __shared__ unsigned short b_s[128][72];   // 18 KB
    int t = threadIdx.x;
    int wave = t >> 6, lane = t & 63;
    int n16 = lane & 15, quad = lane >> 4;
    int row0 = blockIdx.x * 64;

    int arow = t >> 2, aseg = t & 3;   // A: 64 rows, 4 threads/row, 16 cols each
    int brow = t >> 1, bseg = t & 1;   // B: 128 rows, 2 threads/row, 32 cols each
    int agr = row0 + arow;
    bool aval = agr < M;
    const unsigned short* arowp0 = A0 + (size_t)agr * ka0;
    const unsigned short* arowp1 = A1 ? (A1 + (size_t)agr * Dh) : arowp0;
    const unsigned short* browp  = BT + (size_t)brow * K;

    f32x4 acc[8];
    #pragma unroll
    for (int j = 0; j < 8; j++) acc[j] = (f32x4){0.f, 0.f, 0.f, 0.f};

    int nchunk = K >> 6;
    uint4 ra0, ra1, rb0, rb1, rb2, rb3;
    uint4 zz = make_uint4(0u, 0u, 0u, 0u);

    // prefetch chunk 0
    {
        int kk = aseg * 16;
        const uint4* gp = (const uint4*)((kk < ka0) ? &arowp0[kk] : &arowp1[kk - ka0]);
        ra0 = aval ? gp[0] : zz;
        ra1 = aval ? gp[1] : zz;
        const uint4* bp = (const uint4*)&browp[bseg * 32];
        rb0 = bp[0]; rb1 = bp[1]; rb2 = bp[2]; rb3 = bp[3];
    }

    for (int ch = 0; ch < nchunk; ch++) {
        // commit prefetched chunk to LDS
        *(uint4*)&a_s[arow][aseg * 16]     = ra0;
        *(uint4*)&a_s[arow][aseg * 16 + 8] = ra1;
        *(uint4*)&b_s[brow][bseg * 32]      = rb0;
        *(uint4*)&b_s[brow][bseg * 32 + 8]  = rb1;
        *(uint4*)&b_s[brow][bseg * 32 + 16] = rb2;
        *(uint4*)&b_s[brow][bseg * 32 + 24] = rb3;
        __syncthreads();
        // issue next chunk's loads (latency hides under MFMA below)
        if (ch + 1 < nchunk) {
            int kk = (ch + 1) * 64 + aseg * 16;
            const uint4* gp = (const uint4*)((kk < ka0) ? &arowp0[kk] : &arowp1[kk - ka0]);
            ra0 = aval ? gp[0] : zz;
            ra1 = aval ? gp[1] : zz;
            const uint4* bp = (const uint4*)&browp[(ch + 1) * 64 + bseg * 32];
            rb0 = bp[0]; rb1 = bp[1]; rb2 = bp[2]; rb3 = bp[3];
        }
        #pragma unroll
        for (int ks = 0; ks < 2; ks++) {
            bf16x8 af, bfr[8];
            af = *(const bf16x8*)&a_s[wave * 16 + n16][ks * 32 + quad * 8];
            #pragma unroll
            for (int j = 0; j < 8; j++)
                bfr[j] = *(const bf16x8*)&b_s[j * 16 + n16][ks * 32 + quad * 8];
            #pragma unroll
            for (int j = 0; j < 8; j++)
                acc[j] = __builtin_amdgcn_mfma_f32_16x16x32_bf16(
                    af, bfr[j], acc[j], 0, 0, 0);
        }
        __syncthreads();
    }

    float sj[8], tj[8];
    #pragma unroll
    for (int j = 0; j < 8; j++) {
        int col = j * 16 + n16;
        sj[j] = sc[col]; tj[j] = sh[col];
    }
    #pragma unroll
    for (int v = 0; v < 4; v++) {
        int gr = row0 + wave * 16 + quad * 4 + v;
        if (gr < M) {
            #pragma unroll
            for (int j = 0; j < 8; j++) {
                float y = acc[j][v] * sj[j] + tj[j];
                if (do_relu) y = fmaxf(y, 0.f);
                int col = j * 16 + n16;
                if (out_fp32) ((float*)outp)[(size_t)gr * Dh + col] = y;
                else ((unsigned short*)outp)[(size_t)gr * Dh + col] = f2bf(y);
            }
        }
    }
}

// ---------------------------------------------------------------------------
// count: per-(dst,etype) histogram; atomic return value = edge rank within
// its bucket (enables atomic-free fill; round-9 measured win).
// ---------------------------------------------------------------------------
__global__ __launch_bounds__(256) void count_kernel(
    const int* __restrict__ dst, const int* __restrict__ etype,
    int* __restrict__ counts, unsigned short* __restrict__ rank)
{
    int idx = blockIdx.x * 256 + threadIdx.x;   // [0, EE/4)
    if (idx >= EE / 4) return;
    int4 d = ((const int4*)dst)[idx];
    int4 t = ((const int4*)etype)[idx];
    int r0 = atomicAdd(&counts[d.x * RR + t.x], 1);
    int r1 = atomicAdd(&counts[d.y * RR + t.y], 1);
    int r2 = atomicAdd(&counts[d.z * RR + t.z], 1);
    int r3 = atomicAdd(&counts[d.w * RR + t.w], 1);
    ((ushort4*)rank)[idx] = make_ushort4((unsigned short)r0, (unsigned short)r1,
                                         (unsigned short)r2, (unsigned short)r3);
}

// fused: per-node norm + degree + block-level exclusive scan.
// Also converts counts[n*8+r] IN PLACE to the exclusive per-type prefix.
__global__ __launch_bounds__(256) void norm_scan1_kernel(
    int* __restrict__ counts, float* __restrict__ node_norm,
    int* __restrict__ row_ptr, int* __restrict__ bsum)
{
    __shared__ int s[256];
    int t = threadIdx.x;
    int n = blockIdx.x * 256 + t;
    int total = 0; float norm = 0.f;
    if (n < NN) {
        int pre[RR];
        #pragma unroll
        for (int r = 0; r < RR; r++) {
            int c = counts[n * RR + r];
            pre[r] = total;                      // exclusive prefix
            total += c;
            if (c > 0) norm = 1.0f / (float)c;   // later r overwrites (ref semantics)
        }
        #pragma unroll
        for (int r = 0; r < RR; r++) counts[n * RR + r] = pre[r];
        node_norm[n] = norm;
    }
    s[t] = total;
    __syncthreads();
    #pragma unroll
    for (int off = 1; off < 256; off <<= 1) {
        int v = (t >= off) ? s[t - off] : 0;
        __syncthreads();
        s[t] += v;
        __syncthreads();
    }
    if (n < NN) row_ptr[n] = s[t] - total;
    if (t == 255) bsum[blockIdx.x] = s[255];
}

// scan2 folded in: every block redundantly prefix-scans the 196 bsums in LDS
// (196 ints -- trivial), removing the former 1-block scan2 dispatch bubble.
// Finalizes row_ptr AND folds the global row base into the per-type offsets.
__global__ __launch_bounds__(256) void scan3_kernel(
    int* __restrict__ row_ptr, int* __restrict__ counts,
    const int* __restrict__ bsum)
{
    __shared__ int s[256];
    int t = threadIdx.x;
    int d = (t < NBLK) ? bsum[t] : 0;
    s[t] = d;
    __syncthreads();
    #pragma unroll
    for (int off = 1; off < 256; off <<= 1) {
        int v = (t >= off) ? s[t - off] : 0;
        __syncthreads();
        s[t] += v;
        __syncthreads();
    }
    int bid = blockIdx.x;
    int boff = (bid == 0) ? 0 : s[bid - 1];      // exclusive block offset
    int n = bid * 256 + t;
    if (n < NN) {
        int v = row_ptr[n] + boff;
        row_ptr[n] = v;
        #pragma unroll
        for (int r = 0; r < RR; r++) counts[n * RR + r] += v;
    }
    if (bid == 0 && t == 0) row_ptr[NN] = EE;
}

// atomic-free fill: pos = counts[dst*8+et] + rank[e].
__global__ __launch_bounds__(256) void fill_kernel(
    const int* __restrict__ src, const int* __restrict__ dst,
    const int* __restrict__ etype, const unsigned short* __restrict__ rank,
    const int* __restrict__ counts, unsigned* __restrict__ packed)
{
    int idx = blockIdx.x * 256 + threadIdx.x;   // [0, EE/4)
    if (idx >= EE / 4) return;
    int4 d  = ((const int4*)dst)[idx];
    int4 sr = ((const int4*)src)[idx];
    int4 et = ((const int4*)etype)[idx];
    ushort4 rk = ((const ushort4*)rank)[idx];
    int p0 = counts[d.x * RR + et.x] + rk.x;
    int p1 = counts[d.y * RR + et.y] + rk.y;
    int p2 = counts[d.z * RR + et.z] + rk.z;
    int p3 = counts[d.w * RR + et.w] + rk.w;
    packed[p0] = (unsigned)sr.x | ((unsigned)et.x << 16);
    packed[p1] = (unsigned)sr.y | ((unsigned)et.y << 16);
    packed[p2] = (unsigned)sr.z | ((unsigned)et.z << 16);
    packed[p3] = (unsigned)sr.w | ((unsigned)et.w << 16);
}

// ---------------------------------------------------------------------------
// Basis-space aggregation: one wave per node, lane owns cols (2l, 2l+1).
//   aggB[n, b, :] = norm[n] * sum_{e into n} w_coe[et_e, b] * h[src_e, :]
// Round-13 measured optimum (40.8us): 8-wide batches, wave-uniform edges,
// f32x2 pk_fma, masked tail, 12500 blocks. Five variants tried (readfirstlane,
// pair-split, 16-wide, grid-stride) -- all neutral or worse. CONVERGED.
// ---------------------------------------------------------------------------
__global__ __launch_bounds__(256) void agg_basis_kernel(
    const unsigned* __restrict__ h32, const int* __restrict__ row_ptr,
    const unsigned* __restrict__ packed, const float* __restrict__ node_norm,
    const float* __restrict__ wco,         // this layer's [8][4] coefficients
    unsigned* __restrict__ aggB)           // [NN][256] u32 = [NN][512] bf16
{
    __shared__ float4 co_s[RR];
    int t = threadIdx.x;
    if (t < RR) co_s[t] = ((const float4*)wco)[t];
    __syncthreads();
    int wave = t >> 6, lane = t & 63;
    int n = blockIdx.x * 4 + wave;
    if (n >= NN) return;
    int s = row_ptr[n];
    int e = row_ptr[n + 1];
    f32x2 a[BB];
    #pragma unroll
    for (int b = 0; b < BB; b++) a[b] = (f32x2){0.f, 0.f};
    int i = s;
    for (; i + 8 <= e; i += 8) {
        unsigned p[8], hv[8];
        #pragma unroll
        for (int k = 0; k < 8; k++) p[k] = packed[i + k];
        #pragma unroll
        for (int k = 0; k < 8; k++)
            hv[k] = h32[(size_t)(p[k] & 0xffffu) * 64 + lane];
        #pragma unroll
        for (int k = 0; k < 8; k++) {
            float4 co = co_s[p[k] >> 16];
            f32x2 v = (f32x2){ __uint_as_float(hv[k] << 16),
                               __uint_as_float(hv[k] & 0xffff0000u) };
            a[0] += co.x * v;
            a[1] += co.y * v;
            a[2] += co.z * v;
            a[3] += co.w * v;
        }
    }
    if (i < e) {
        unsigned p[8], hv[8];
        #pragma unroll
        for (int k = 0; k < 8; k++) {
            int j = i + k;
            p[k] = packed[j < e ? j : (e - 1)];
        }
        #pragma unroll
        for (int k = 0; k < 8; k++)
            hv[k] = h32[(size_t)(p[k] & 0xffffu) * 64 + lane];
        #pragma unroll
        for (int k = 0; k < 8; k++) {
            float vm = (i + k < e) ? 1.f : 0.f;
            float4 co = co_s[p[k] >> 16];
            f32x2 v = (f32x2){ __uint_as_float(hv[k] << 16) * vm,
                               __uint_as_float(hv[k] & 0xffff0000u) * vm };
            a[0] += co.x * v;
            a[1] += co.y * v;
            a[2] += co.z * v;
            a[3] += co.w * v;
        }
    }
    float norm = node_norm[n];
    #pragma unroll
    for (int b = 0; b < BB; b++) {
        unsigned o = (unsigned)f2bf(a[b].x * norm) |
                     ((unsigned)f2bf(a[b].y * norm) << 16);
        aggB[(size_t)n * 256 + b * 64 + lane] = o;
    }
}

// ---------------------------------------------------------------------------
extern "C" void kernel_launch(void* const* d_in, const int* in_sizes, int n_in,
                              void* d_out, int out_size, void* d_ws, size_t ws_size,
                              hipStream_t stream)
{
    const float* node_feat = (const float*)d_in[0];
    const float* W_emb     = (const float*)d_in[1];
    const float* b_emb     = (const float*)d_in[2];
    const float* bases     = (const float*)d_in[3];
    const float* w_coe     = (const float*)d_in[4];
    const float* self_loop = (const float*)d_in[5];
    const float* bn_gamma  = (const float*)d_in[6];
    const float* bn_beta   = (const float*)d_in[7];
    const float* bn_mean   = (const float*)d_in[8];
    const float* bn_var    = (const float*)d_in[9];
    const int*   src       = (const int*)d_in[10];
    const int*   dst       = (const int*)d_in[11];
    const int*   etype     = (const int*)d_in[12];

    char* ws = (char*)d_ws;
    size_t off = 0;
    unsigned short* h0 = (unsigned short*)(ws + off);     off += (size_t)NN * Dh * 2;        // 12.8 MB
    unsigned short* h1 = (unsigned short*)(ws + off);     off += (size_t)NN * Dh * 2;        // 12.8 MB
    unsigned short* nf_bf = (unsigned short*)(ws + off);  off += (size_t)NN * Dh * 2;        // 12.8 MB
    unsigned short* aggB = (unsigned short*)(ws + off);   off += (size_t)NN * KA0 * 2;       // 51.2 MB
    unsigned short* BT = (unsigned short*)(ws + off);     off += (size_t)LL * Dh * KTOT * 2; // 320 KB
    unsigned short* WembT = (unsigned short*)(ws + off);  off += (size_t)Dh * Dh * 2;        // 32 KB
    float* sc = (float*)(ws + off);                       off += 3 * Dh * 4;
    float* sh = (float*)(ws + off);                       off += 3 * Dh * 4;
    float* node_norm = (float*)(ws + off);                off += (size_t)NN * 4;
    int* counts = (int*)(ws + off);                       off += (size_t)NR * 4;             // 1.6 MB
    int* row_ptr = (int*)(ws + off);                      off += ((size_t)NN + 4) * 4;
    unsigned short* rank = (unsigned short*)(ws + off);   off += (size_t)EE * 2;             // 1.6 MB
    int* bsum = (int*)(ws + off);                         off += 256 * 4;
    unsigned* packed = (unsigned*)(ws + off);             off += (size_t)EE * 4 + 64;        // 3.2 MB

    const int e4_blocks = (EE / 4 + 255) / 256;      // 782
    const int node_blocks = (NN + 255) / 256;        // 196
    const int prep_blocks = (PREP_TOT + 255) / 256;  // 4222
    const int gemm_blocks = (NN + 63) / 64;          // 782
    const int agg_blocks = (NN + 3) / 4;             // 12500

    // fused prep (nf cast, BT, WembT, epilogue, counts zero)
    prep_kernel<<<prep_blocks, 256, 0, stream>>>(
        node_feat, bases, self_loop, W_emb, b_emb,
        bn_gamma, bn_beta, bn_mean, bn_var,
        nf_bf, BT, WembT, sc, sh, counts);

    // graph structure
    count_kernel<<<e4_blocks, 256, 0, stream>>>(dst, etype, counts, rank);
    norm_scan1_kernel<<<node_blocks, 256, 0, stream>>>(counts, node_norm, row_ptr, bsum);
    scan3_kernel<<<node_blocks, 256, 0, stream>>>(row_ptr, counts, bsum);
    fill_kernel<<<e4_blocks, 256, 0, stream>>>(src, dst, etype, rank, counts, packed);

    // embed: h0 = bf16(nf @ W_emb + b_emb)
    gemm_bn_kernel<<<gemm_blocks, 256, 0, stream>>>(
        nf_bf, Dh, nullptr, WembT, Dh, sc, sh, h0, 0, 0, NN);

    // layer 0
    agg_basis_kernel<<<agg_blocks, 256, 0, stream>>>(
        (const unsigned*)h0, row_ptr, packed, node_norm, w_coe, (unsigned*)aggB);
    gemm_bn_kernel<<<gemm_blocks, 256, 0, stream>>>(
        aggB, KA0, h0, BT, KTOT, sc + Dh, sh + Dh, h1, 0, 1, NN);

    // layer 1
    agg_basis_kernel<<<agg_blocks, 256, 0, stream>>>(
        (const unsigned*)h1, row_ptr, packed, node_norm, w_coe + RR * BB, (unsigned*)aggB);
    gemm_bn_kernel<<<gemm_blocks, 256, 0, stream>>>(
        aggB, KA0, h1, BT + Dh * KTOT, KTOT, sc + 2 * Dh, sh + 2 * Dh, d_out, 1, 1, NN);
}